// Round 4
// baseline (337.086 us; speedup 1.0000x reference)
//
#include <hip/hip_runtime.h>
#include <math.h>

#define BB 32
#define DD 2048
#define NKVH 4
#define HDIM 128
#define MAXS 4096
#define FFD 8192
#define POS 4095
#define EPSV 1e-5f
#define SCALE 0.08838834764831845f
#define ASPLIT 32
#define SPOS 128   // positions per split

// workspace offsets (floats)
#define OFF_QT   0u        // 2048 x 32 (transposed q)
#define OFF_KT   65536u    // 512 x 32
#define OFF_VT   81920u    // 512 x 32
#define OFF_G1   98304u    // 8192 x 32
#define OFF_G2   360448u   // 8192 x 32
#define ZERO_N   622592u   // contiguous atomic-target region [0, ZERO_N)
#define OFF_XAT  622592u   // 2048 x 32
#define OFF_RK   688128u   // 32 x 4 x 128
#define OFF_RV   704512u
#define OFF_PML  720896u   // 32*32*16 x {m,l} = 32768
#define OFF_PACC 753664u   // 32*32*16 x 128 = 2097152
#define OFF_YT   2850816u  // 2048 x 32
#define OFF_H    2916352u  // 32 x 2048 (normal)
#define OFF_XFT  2981888u  // 2048 x 32

#define REP32(M) M(0) M(1) M(2) M(3) M(4) M(5) M(6) M(7) M(8) M(9) M(10) M(11) M(12) M(13) M(14) M(15) M(16) M(17) M(18) M(19) M(20) M(21) M(22) M(23) M(24) M(25) M(26) M(27) M(28) M(29) M(30) M(31)
#define REP32A(M,X) M(0,X) M(1,X) M(2,X) M(3,X) M(4,X) M(5,X) M(6,X) M(7,X) M(8,X) M(9,X) M(10,X) M(11,X) M(12,X) M(13,X) M(14,X) M(15,X) M(16,X) M(17,X) M(18,X) M(19,X) M(20,X) M(21,X) M(22,X) M(23,X) M(24,X) M(25,X) M(26,X) M(27,X) M(28,X) M(29,X) M(30,X) M(31,X)

#define DECLA(i) float a##i = 0.f;
#define FMA1(i,k) a##i = fmaf(ap[(k)*32 + (i)], w##k, a##i);
#define STORET(i) tl[i] = a##i;
#define ATOMN(i) atomicAdd(C + (size_t)(i)*N + n, a##i);

// 32-batch GEMV: C[b][n] += sum_d At[d][b] * W[d][n].
template<int N, int CH, bool TOUT>
__device__ __forceinline__ void gemv_body(const float* __restrict__ At,
                                          const float* __restrict__ W,
                                          float* __restrict__ C, int colblk,
                                          float* tile) {
    int tid = (int)threadIdx.x;
    int n = colblk * 256 + tid;
    int d0 = blockIdx.y * CH;
    const float* Wp = W + (size_t)d0 * N + n;
    const float* ap = At + (size_t)d0 * 32;
    REP32(DECLA)
#pragma unroll 4
    for (int dd = 0; dd < CH; dd += 4) {
        float w0 = Wp[0];
        float w1 = Wp[(size_t)N];
        float w2 = Wp[(size_t)N * 2];
        float w3 = Wp[(size_t)N * 3];
        REP32A(FMA1, 0)
        REP32A(FMA1, 1)
        REP32A(FMA1, 2)
        REP32A(FMA1, 3)
        Wp += (size_t)N * 4;
        ap += 128;
    }
    if constexpr (TOUT) {
        float* tl = tile + tid * 33;
        REP32(STORET)
        __syncthreads();
        float* cb = C + (size_t)colblk * 256 * 32;
#pragma unroll
        for (int i = 0; i < 32; ++i) {
            int f = i * 256 + tid;
            atomicAdd(cb + f, tile[(f >> 5) * 33 + (f & 31)]);
        }
    } else {
        REP32(ATOMN)
    }
}

template<int N, int CH, bool TOUT>
__global__ __launch_bounds__(256) void gemv32_kernel(const float* __restrict__ At,
                                                     const float* __restrict__ W,
                                                     float* __restrict__ C) {
    if constexpr (TOUT) {
        __shared__ float tile[256 * 33];
        gemv_body<N, CH, true>(At, W, C, blockIdx.x, tile);
    } else {
        gemv_body<N, CH, false>(At, W, C, blockIdx.x, nullptr);
    }
}

template<int N, int CH, int HALF>
__global__ __launch_bounds__(256) void gemv32_dual_kernel(const float* __restrict__ At,
        const float* __restrict__ W0, const float* __restrict__ W1,
        float* __restrict__ C0, float* __restrict__ C1) {
    __shared__ float tile[256 * 33];
    int bx = blockIdx.x;
    if (bx < HALF) gemv_body<N, CH, true>(At, W0, C0, bx, tile);
    else           gemv_body<N, CH, true>(At, W1, C1, bx - HALF, tile);
}

__global__ void zero_kernel(float* __restrict__ p) {
    p[blockIdx.x * 256 + threadIdx.x] = 0.f;
}

// rmsnorm row b: outT[d][b] = norm; cpy[b][d] = raw input (residual)
__global__ void rmsnorm_kernel(const float* __restrict__ in, const float* __restrict__ g,
                               float* __restrict__ outT, float* __restrict__ cpy) {
    int b = blockIdx.x;
    int tid = threadIdx.x; // 256
    const float* row = in + b * DD;
    float v[8];
    float ss = 0.f;
#pragma unroll
    for (int i = 0; i < 8; ++i) { v[i] = row[tid + i * 256]; ss += v[i] * v[i]; }
#pragma unroll
    for (int off = 32; off; off >>= 1) ss += __shfl_xor(ss, off);
    __shared__ float red[4];
    if ((tid & 63) == 0) red[tid >> 6] = ss;
    __syncthreads();
    ss = red[0] + red[1] + red[2] + red[3];
    float scale = rsqrtf(ss * (1.f / DD) + EPSV);
#pragma unroll
    for (int i = 0; i < 8; ++i) {
        int idx = tid + i * 256;
        outT[(size_t)idx * 32 + b] = v[i] * g[idx] * scale;
        if (cpy) cpy[b * DD + idx] = v[i];
    }
}

// rope on new k and v (reference ropes BOTH k and v; q is NOT roped)
__global__ void rope_kernel(const float* __restrict__ kT, const float* __restrict__ vT,
                            const float* __restrict__ cosb, const float* __restrict__ sinb,
                            float* __restrict__ rk, float* __restrict__ rv) {
    int idx = blockIdx.x * 256 + threadIdx.x; // 8192
    int b = idx >> 8, rem = idx & 255;
    int kvh = rem >> 6, i = rem & 63;
    float c = cosb[i], s = sinb[i];
    int col = kvh * HDIM + 2 * i;
    float k0 = kT[(size_t)col * 32 + b], k1 = kT[(size_t)(col + 1) * 32 + b];
    float v0 = vT[(size_t)col * 32 + b], v1 = vT[(size_t)(col + 1) * 32 + b];
    int o = (b * NKVH + kvh) * HDIM + 2 * i;
    rk[o] = k0 * c - k1 * s; rk[o + 1] = k0 * s + k1 * c;
    rv[o] = v0 * c - v1 * s; rv[o + 1] = v0 * s + v1 * c;
}

// attention partial: grid 1024 = (b, 32 splits of 128 positions), all 4 kvh per block.
// Memory access is a pure linear sweep: float4 addr = base + iter*4KB + tid*16B.
// Thread's (kvh, c) are invariant: kvh=(tid>>5)&3, c=tid&31, pos parity hi=tid>>7.
__global__ __launch_bounds__(256) void attn_partial_kernel(
    const float* __restrict__ qT, const float* __restrict__ kc, const float* __restrict__ vc,
    const float* __restrict__ rk, const float* __restrict__ rv,
    float* __restrict__ pml, float* __restrict__ pacc) {
    int bid = blockIdx.x;
    int split = bid & 31, b = bid >> 5;
    int tid = threadIdx.x;
    int kvh = (tid >> 5) & 3;
    int c = tid & 31;
    int hi = tid >> 7;
    __shared__ float p_s[16][SPOS];   // 8 KB scores
    __shared__ float red[128][17];    // 8.5 KB PV pair-reduce

    // q fragments: 4 heads (of this kvh) x float4 (dims c*4..c*4+3), registers only
    float4 q4[4];
#pragma unroll
    for (int h = 0; h < 4; ++h) {
        int col = (kvh * 4 + h) * HDIM + c * 4;
        q4[h].x = qT[(size_t)(col + 0) * 32 + b];
        q4[h].y = qT[(size_t)(col + 1) * 32 + b];
        q4[h].z = qT[(size_t)(col + 2) * 32 + b];
        q4[h].w = qT[(size_t)(col + 3) * 32 + b];
    }
    int t0 = split * SPOS;
    const float* kbase = kc + (size_t)(b * MAXS + t0) * (NKVH * HDIM);
    const float* vbase = vc + (size_t)(b * MAXS + t0) * (NKVH * HDIM);

#define QK_BODY(SRC, POSL)                                                      \
    {                                                                           \
        float4 kk = *(const float4*)(SRC);                                      \
        float r0 = kk.x * q4[0].x + kk.y * q4[0].y + kk.z * q4[0].z + kk.w * q4[0].w; \
        float r1 = kk.x * q4[1].x + kk.y * q4[1].y + kk.z * q4[1].z + kk.w * q4[1].w; \
        float r2 = kk.x * q4[2].x + kk.y * q4[2].y + kk.z * q4[2].z + kk.w * q4[2].w; \
        float r3 = kk.x * q4[3].x + kk.y * q4[3].y + kk.z * q4[3].z + kk.w * q4[3].w; \
        _Pragma("unroll")                                                       \
        for (int m = 1; m < 32; m <<= 1) {                                      \
            r0 += __shfl_xor(r0, m); r1 += __shfl_xor(r1, m);                   \
            r2 += __shfl_xor(r2, m); r3 += __shfl_xor(r3, m);                   \
        }                                                                       \
        if (c == 0) {                                                           \
            p_s[kvh * 4 + 0][POSL] = r0 * SCALE;                                \
            p_s[kvh * 4 + 1][POSL] = r1 * SCALE;                                \
            p_s[kvh * 4 + 2][POSL] = r2 * SCALE;                                \
            p_s[kvh * 4 + 3][POSL] = r3 * SCALE;                                \
        }                                                                       \
    }

    // QK phase: iters 0..62 unconditional linear sweep; iter 63 handles POS
#pragma unroll 8
    for (int iter = 0; iter < 63; ++iter) {
        QK_BODY(kbase + iter * 1024 + tid * 4, iter * 2 + hi)
    }
    {
        int posl = 126 + hi;
        const float* src = (t0 + posl == POS)
            ? rk + (size_t)(b * NKVH + kvh) * HDIM + c * 4
            : kbase + 63 * 1024 + tid * 4;
        QK_BODY(src, posl)
    }
    __syncthreads();

    // softmax over SPOS positions per head: wave w handles heads 4w..4w+3
    {
        int w = tid >> 6, lane = tid & 63;
#pragma unroll
        for (int hh = 0; hh < 4; ++hh) {
            int h = w * 4 + hh;
            float e0 = p_s[h][lane], e1 = p_s[h][lane + 64];
            float m = fmaxf(e0, e1);
#pragma unroll
            for (int off = 32; off; off >>= 1) m = fmaxf(m, __shfl_xor(m, off));
            e0 = __expf(e0 - m); e1 = __expf(e1 - m);
            p_s[h][lane] = e0; p_s[h][lane + 64] = e1;
            float l = e0 + e1;
#pragma unroll
            for (int off = 32; off; off >>= 1) l += __shfl_xor(l, off);
            if (lane == 0) {
                int idx = ((b * ASPLIT + split) * 16 + h) * 2;
                pml[idx] = m; pml[idx + 1] = l;
            }
        }
    }
    __syncthreads();

    // PV phase: same linear sweep; acc = 4 heads x float4 in registers
    float4 a0 = {0, 0, 0, 0}, a1 = a0, a2 = a0, a3 = a0;
#define PV_BODY(SRC, POSL)                                                      \
    {                                                                           \
        float4 vv = *(const float4*)(SRC);                                      \
        float p0 = p_s[kvh * 4 + 0][POSL], p1 = p_s[kvh * 4 + 1][POSL];         \
        float p2 = p_s[kvh * 4 + 2][POSL], p3 = p_s[kvh * 4 + 3][POSL];         \
        a0.x = fmaf(p0, vv.x, a0.x); a0.y = fmaf(p0, vv.y, a0.y);               \
        a0.z = fmaf(p0, vv.z, a0.z); a0.w = fmaf(p0, vv.w, a0.w);               \
        a1.x = fmaf(p1, vv.x, a1.x); a1.y = fmaf(p1, vv.y, a1.y);               \
        a1.z = fmaf(p1, vv.z, a1.z); a1.w = fmaf(p1, vv.w, a1.w);               \
        a2.x = fmaf(p2, vv.x, a2.x); a2.y = fmaf(p2, vv.y, a2.y);               \
        a2.z = fmaf(p2, vv.z, a2.z); a2.w = fmaf(p2, vv.w, a2.w);               \
        a3.x = fmaf(p3, vv.x, a3.x); a3.y = fmaf(p3, vv.y, a3.y);               \
        a3.z = fmaf(p3, vv.z, a3.z); a3.w = fmaf(p3, vv.w, a3.w);               \
    }
#pragma unroll 8
    for (int iter = 0; iter < 63; ++iter) {
        PV_BODY(vbase + iter * 1024 + tid * 4, iter * 2 + hi)
    }
    {
        int posl = 126 + hi;
        const float* src = (t0 + posl == POS)
            ? rv + (size_t)(b * NKVH + kvh) * HDIM + c * 4
            : vbase + 63 * 1024 + tid * 4;
        PV_BODY(src, posl)
    }
    // pair-reduce (tid, tid+128) which share (kvh, c) and cover complementary pos
    if (tid >= 128) {
        float* r = &red[tid - 128][0];
        *(float4*)(r + 0) = a0; *(float4*)(r + 4) = a1;
        *(float4*)(r + 8) = a2; *(float4*)(r + 12) = a3;
    }
    __syncthreads();
    if (tid < 128) {
        const float* r = &red[tid][0];
        a0.x += r[0];  a0.y += r[1];  a0.z += r[2];  a0.w += r[3];
        a1.x += r[4];  a1.y += r[5];  a1.z += r[6];  a1.w += r[7];
        a2.x += r[8];  a2.y += r[9];  a2.z += r[10]; a2.w += r[11];
        a3.x += r[12]; a3.y += r[13]; a3.z += r[14]; a3.w += r[15];
        size_t base = ((size_t)(b * ASPLIT + split) * 16 + kvh * 4) * HDIM + c * 4;
        *(float4*)(pacc + base + 0 * HDIM) = a0;
        *(float4*)(pacc + base + 1 * HDIM) = a1;
        *(float4*)(pacc + base + 2 * HDIM) = a2;
        *(float4*)(pacc + base + 3 * HDIM) = a3;
    }
}

// combine split partials: grid 512 = (b, h), 128 threads; writes yT
__global__ void attn_combine_kernel(const float* __restrict__ pml,
                                    const float* __restrict__ pacc, float* __restrict__ yT) {
    int bid = blockIdx.x;
    int b = bid >> 4, h = bid & 15;
    int d = threadIdx.x;
    float M = -INFINITY;
#pragma unroll 8
    for (int s = 0; s < ASPLIT; ++s)
        M = fmaxf(M, pml[((b * ASPLIT + s) * 16 + h) * 2]);
    float denom = 0.f, acc = 0.f;
#pragma unroll 4
    for (int s = 0; s < ASPLIT; ++s) {
        int idx = (b * ASPLIT + s) * 16 + h;
        float e = __expf(pml[idx * 2] - M);
        denom += pml[idx * 2 + 1] * e;
        acc += e * pacc[(size_t)idx * HDIM + d];
    }
    yT[(size_t)(h * HDIM + d) * 32 + b] = acc / denom;
}

__global__ void silu_mul_kernel(float* __restrict__ g1, const float* __restrict__ g2) {
    int i = blockIdx.x * 256 + threadIdx.x; // 262144
    float a = g1[i], bb = g2[i];
    g1[i] = a * bb / (1.f + __expf(-a));
}

extern "C" void kernel_launch(void* const* d_in, const int* in_sizes, int n_in,
                              void* d_out, int out_size, void* d_ws, size_t ws_size,
                              hipStream_t stream) {
    (void)in_sizes; (void)n_in; (void)out_size; (void)ws_size;
    const float* x    = (const float*)d_in[0];
    const float* cosb = (const float*)d_in[1];
    const float* sinb = (const float*)d_in[2];
    const float* kc   = (const float*)d_in[3];
    const float* vc   = (const float*)d_in[4];
    const float* wra  = (const float*)d_in[5];
    const float* wq   = (const float*)d_in[6];
    const float* wk   = (const float*)d_in[7];
    const float* wv   = (const float*)d_in[8];
    const float* wo   = (const float*)d_in[9];
    const float* wrf  = (const float*)d_in[10];
    const float* w1   = (const float*)d_in[11];
    const float* w2   = (const float*)d_in[12];
    const float* w3   = (const float*)d_in[13];
    float* out = (float*)d_out;
    float* ws  = (float*)d_ws;

    float* qT   = ws + OFF_QT;
    float* kT   = ws + OFF_KT;
    float* vT   = ws + OFF_VT;
    float* g1T  = ws + OFF_G1;
    float* g2T  = ws + OFF_G2;
    float* xaT  = ws + OFF_XAT;
    float* rk   = ws + OFF_RK;
    float* rv   = ws + OFF_RV;
    float* pml  = ws + OFF_PML;
    float* pacc = ws + OFF_PACC;
    float* yT   = ws + OFF_YT;
    float* h    = ws + OFF_H;
    float* xfT  = ws + OFF_XFT;

    // zero all atomic-accumulated buffers (qT,kT,vT,g1T,g2T contiguous)
    zero_kernel<<<ZERO_N / 256, 256, 0, stream>>>(ws);

    // xaT = rmsnorm(x)^T, h = x
    rmsnorm_kernel<<<32, 256, 0, stream>>>(x, wra, xaT, h);
    // q,k,v (transposed outputs)
    gemv32_kernel<2048, 32, true><<<dim3(8, 64), 256, 0, stream>>>(xaT, wq, qT);
    gemv32_dual_kernel<512, 32, 2><<<dim3(4, 64), 256, 0, stream>>>(xaT, wk, wv, kT, vT);
    // rope new k,v (cache NOT mutated)
    rope_kernel<<<32, 256, 0, stream>>>(kT, vT, cosb, sinb, rk, rv);
    // attention
    attn_partial_kernel<<<1024, 256, 0, stream>>>(qT, kc, vc, rk, rv, pml, pacc);
    attn_combine_kernel<<<512, 128, 0, stream>>>(pml, pacc, yT);
    // h = x + y @ wo
    gemv32_kernel<2048, 32, false><<<dim3(8, 64), 256, 0, stream>>>(yT, wo, h);
    // xfT = rmsnorm(h)^T, out = h
    rmsnorm_kernel<<<32, 256, 0, stream>>>(h, wrf, xfT, out);
    // g1 = xf@w1, g2 = xf@w2 (transposed outputs)
    gemv32_dual_kernel<8192, 128, 32><<<dim3(64, 16), 256, 0, stream>>>(xfT, w1, w2, g1T, g2T);
    // g1 = silu(g1)*g2 (elementwise, layout-agnostic)
    silu_mul_kernel<<<1024, 256, 0, stream>>>(g1T, g2T);
    // out += g1 @ w3
    gemv32_kernel<2048, 128, false><<<dim3(8, 64), 256, 0, stream>>>(g1T, w3, out);
}

// Round 5
// 309.718 us; speedup vs baseline: 1.0884x; 1.0884x over previous
//
#include <hip/hip_runtime.h>
#include <math.h>

#define BB 32
#define DD 2048
#define NKVH 4
#define HDIM 128
#define MAXS 4096
#define FFD 8192
#define POS 4095
#define EPSV 1e-5f
#define SCALE 0.08838834764831845f
#define ASPLIT 32
#define SPOS 128   // positions per split

// workspace offsets (floats)
#define OFF_QT   0u        // 32 x 2048 q (NORMAL layout, atomic target)
#define OFF_KT   65536u    // 512 x 32 (transposed)
#define OFF_VT   81920u    // 512 x 32
#define OFF_G1   98304u    // 8192 x 32
#define OFF_G2   360448u   // 8192 x 32
#define ZERO_N   622592u   // contiguous atomic-target region [0, ZERO_N)
#define OFF_XAT  622592u   // 2048 x 32
#define OFF_RK   688128u   // 32 x 4 x 128
#define OFF_RV   704512u
#define OFF_PML  720896u   // 32*32*16 x {m,l} = 32768
#define OFF_PACC 753664u   // 32*32*16 x 128 = 2097152
#define OFF_YT   2850816u  // 2048 x 32
#define OFF_H    2916352u  // 32 x 2048 (normal)
#define OFF_XFT  2981888u  // 2048 x 32
#define OFF_KFIX 3047424u  // 32 x 16 x 512 (last-16-pos K records, pos 4095 patched)
#define OFF_VFIX 3309568u  // 32 x 16 x 512

#define VM_WAIT8 asm volatile("s_waitcnt vmcnt(8)" ::: "memory")
#define VM_WAIT0 asm volatile("s_waitcnt vmcnt(0)" ::: "memory")
#define LG_WAIT0 asm volatile("s_waitcnt lgkmcnt(0)" ::: "memory")
#define SCHED0   __builtin_amdgcn_sched_barrier(0)
#define SBAR     __builtin_amdgcn_s_barrier()

#define REP32(M) M(0) M(1) M(2) M(3) M(4) M(5) M(6) M(7) M(8) M(9) M(10) M(11) M(12) M(13) M(14) M(15) M(16) M(17) M(18) M(19) M(20) M(21) M(22) M(23) M(24) M(25) M(26) M(27) M(28) M(29) M(30) M(31)
#define REP32A(M,X) M(0,X) M(1,X) M(2,X) M(3,X) M(4,X) M(5,X) M(6,X) M(7,X) M(8,X) M(9,X) M(10,X) M(11,X) M(12,X) M(13,X) M(14,X) M(15,X) M(16,X) M(17,X) M(18,X) M(19,X) M(20,X) M(21,X) M(22,X) M(23,X) M(24,X) M(25,X) M(26,X) M(27,X) M(28,X) M(29,X) M(30,X) M(31,X)

#define DECLA(i) float a##i = 0.f;
#define FMA1(i,k) a##i = fmaf(ap[(k)*32 + (i)], w##k, a##i);
#define STORET(i) tl[i] = a##i;
#define ATOMN(i) atomicAdd(C + (size_t)(i)*N + n, a##i);

// 32-batch GEMV: C[b][n] += sum_d At[d][b] * W[d][n].
template<int N, int CH, bool TOUT>
__device__ __forceinline__ void gemv_body(const float* __restrict__ At,
                                          const float* __restrict__ W,
                                          float* __restrict__ C, int colblk,
                                          float* tile) {
    int tid = (int)threadIdx.x;
    int n = colblk * 256 + tid;
    int d0 = blockIdx.y * CH;
    const float* Wp = W + (size_t)d0 * N + n;
    const float* ap = At + (size_t)d0 * 32;
    REP32(DECLA)
#pragma unroll 4
    for (int dd = 0; dd < CH; dd += 4) {
        float w0 = Wp[0];
        float w1 = Wp[(size_t)N];
        float w2 = Wp[(size_t)N * 2];
        float w3 = Wp[(size_t)N * 3];
        REP32A(FMA1, 0)
        REP32A(FMA1, 1)
        REP32A(FMA1, 2)
        REP32A(FMA1, 3)
        Wp += (size_t)N * 4;
        ap += 128;
    }
    if constexpr (TOUT) {
        float* tl = tile + tid * 33;
        REP32(STORET)
        __syncthreads();
        float* cb = C + (size_t)colblk * 256 * 32;
#pragma unroll
        for (int i = 0; i < 32; ++i) {
            int f = i * 256 + tid;
            atomicAdd(cb + f, tile[(f >> 5) * 33 + (f & 31)]);
        }
    } else {
        REP32(ATOMN)
    }
}

template<int N, int CH, bool TOUT>
__global__ __launch_bounds__(256) void gemv32_kernel(const float* __restrict__ At,
                                                     const float* __restrict__ W,
                                                     float* __restrict__ C) {
    if constexpr (TOUT) {
        __shared__ float tile[256 * 33];
        gemv_body<N, CH, true>(At, W, C, blockIdx.x, tile);
    } else {
        gemv_body<N, CH, false>(At, W, C, blockIdx.x, nullptr);
    }
}

template<int N, int CH, int HALF>
__global__ __launch_bounds__(256) void gemv32_dual_kernel(const float* __restrict__ At,
        const float* __restrict__ W0, const float* __restrict__ W1,
        float* __restrict__ C0, float* __restrict__ C1) {
    __shared__ float tile[256 * 33];
    int bx = blockIdx.x;
    if (bx < HALF) gemv_body<N, CH, true>(At, W0, C0, bx, tile);
    else           gemv_body<N, CH, true>(At, W1, C1, bx - HALF, tile);
}

__global__ void zero_kernel(float* __restrict__ p) {
    p[blockIdx.x * 256 + threadIdx.x] = 0.f;
}

// rmsnorm row b: outT[d][b] = norm; cpy[b][d] = raw input (residual)
__global__ void rmsnorm_kernel(const float* __restrict__ in, const float* __restrict__ g,
                               float* __restrict__ outT, float* __restrict__ cpy) {
    int b = blockIdx.x;
    int tid = threadIdx.x; // 256
    const float* row = in + b * DD;
    float v[8];
    float ss = 0.f;
#pragma unroll
    for (int i = 0; i < 8; ++i) { v[i] = row[tid + i * 256]; ss += v[i] * v[i]; }
#pragma unroll
    for (int off = 32; off; off >>= 1) ss += __shfl_xor(ss, off);
    __shared__ float red[4];
    if ((tid & 63) == 0) red[tid >> 6] = ss;
    __syncthreads();
    ss = red[0] + red[1] + red[2] + red[3];
    float scale = rsqrtf(ss * (1.f / DD) + EPSV);
#pragma unroll
    for (int i = 0; i < 8; ++i) {
        int idx = tid + i * 256;
        outT[(size_t)idx * 32 + b] = v[i] * g[idx] * scale;
        if (cpy) cpy[b * DD + idx] = v[i];
    }
}

// rope on new k and v (reference ropes BOTH k and v; q is NOT roped)
__global__ void rope_kernel(const float* __restrict__ kT, const float* __restrict__ vT,
                            const float* __restrict__ cosb, const float* __restrict__ sinb,
                            float* __restrict__ rk, float* __restrict__ rv) {
    int idx = blockIdx.x * 256 + threadIdx.x; // 8192
    int b = idx >> 8, rem = idx & 255;
    int kvh = rem >> 6, i = rem & 63;
    float c = cosb[i], s = sinb[i];
    int col = kvh * HDIM + 2 * i;
    float k0 = kT[(size_t)col * 32 + b], k1 = kT[(size_t)(col + 1) * 32 + b];
    float v0 = vT[(size_t)col * 32 + b], v1 = vT[(size_t)(col + 1) * 32 + b];
    int o = (b * NKVH + kvh) * HDIM + 2 * i;
    rk[o] = k0 * c - k1 * s; rk[o + 1] = k0 * s + k1 * c;
    rv[o] = v0 * c - v1 * s; rv[o + 1] = v0 * s + v1 * c;
}

// materialize last-16-position K/V records; pos 4095 comes from rk/rv
// (cache inputs are never mutated). Layout mirrors cache: [b][16][4][128].
__global__ void fixlast_kernel(const float* __restrict__ kc, const float* __restrict__ vc,
                               const float* __restrict__ rk, const float* __restrict__ rv,
                               float* __restrict__ kfix, float* __restrict__ vfix) {
    int idx = blockIdx.x * 256 + threadIdx.x;  // 32*16*512 = 262144
    int b = idx >> 13, rem = idx & 8191;
    int pos = rem >> 9, col = rem & 511;
    int gpos = 4080 + pos;
    float kv, vv;
    if (gpos == POS) {
        kv = rk[b * 512 + col]; vv = rv[b * 512 + col];
    } else {
        size_t o = ((size_t)(b * MAXS + gpos)) * 512 + col;
        kv = kc[o]; vv = vc[o];
    }
    kfix[idx] = kv; vfix[idx] = vv;
}

// attention: grid 1024 = (b, 32 splits of 128 pos), all 4 kvh per block.
// K/V staged to LDS via global_load_lds (no VGPR cost), double-buffered,
// counted vmcnt(8) waits, raw barriers. 16 sub-tiles of 16 pos (8 K + 8 V).
// QK: thread=(pos,head), q row in 128 pre-rotated VGPRs; rotation makes the
// wave's 16 distinct LDS rows hit distinct granules (conflict-free).
// PV: thread=(head,c16), contiguous granule reads (conflict-free).
__global__ __launch_bounds__(256, 2) void attn_stage_kernel(
    const float* __restrict__ qn, const float* __restrict__ kc, const float* __restrict__ vc,
    const float* __restrict__ kfix, const float* __restrict__ vfix,
    float* __restrict__ pml, float* __restrict__ pacc) {
    int split = blockIdx.x & 31, b = blockIdx.x >> 5;
    int tid = threadIdx.x, lane = tid & 63, wv = tid >> 6;
    __shared__ float kbuf[2][8192];   // 2 x 32 KB (16 pos x 4 kvh x 128)
    __shared__ float p_s[128][16];    // [pos][head] scores -> exp
    int qpos = tid >> 4, qhead = tid & 15;
    int qr = qpos * 4 + (qhead >> 2);          // LDS 512B-row id (0..63)
    int vh = tid >> 4, c16 = tid & 15, vkvh = vh >> 2;
    int t0 = split * SPOS;

    // q pre-rotated: qrot[j] = q[b][qhead*128 + ((j+qr)&31)*4 ..]
    float4 qrot[32];
#pragma unroll
    for (int j = 0; j < 32; ++j) {
        int g = (j + qr) & 31;
        qrot[j] = *(const float4*)(qn + (size_t)b * DD + qhead * HDIM + g * 4);
    }
    float4 av0 = {0, 0, 0, 0}, av1 = {0, 0, 0, 0};

    auto stage = [&](int t) {
        int s = t & 7;
        const float* base;
        if (t < 8) base = (split == 31 && s == 7) ? kfix + (size_t)b * 8192
                                                  : kc + ((size_t)b * MAXS + t0 + s * 16) * 512;
        else       base = (split == 31 && s == 7) ? vfix + (size_t)b * 8192
                                                  : vc + ((size_t)b * MAXS + t0 + s * 16) * 512;
        const float* g = base + wv * 2048 + lane * 4;   // per-lane global src
        float* l = &kbuf[t & 1][wv * 2048];             // wave-uniform LDS base
#pragma unroll
        for (int i = 0; i < 8; ++i)
            __builtin_amdgcn_global_load_lds(
                (const __attribute__((address_space(1))) void*)(g + i * 256),
                (__attribute__((address_space(3))) void*)(l + i * 256), 16, 0, 0);
    };

    stage(0);
    for (int t = 0; t < 16; ++t) {
        if (t < 15) { stage(t + 1); VM_WAIT8; } else { VM_WAIT0; }
        SCHED0; SBAR;
        if (t == 8) {
            // softmax: wave w handles heads 4w..4w+3 (same heads it uses in PV)
#pragma unroll
            for (int hh = 0; hh < 4; ++hh) {
                int h = wv * 4 + hh;
                float e0 = p_s[lane][h], e1 = p_s[lane + 64][h];
                float m = fmaxf(e0, e1);
#pragma unroll
                for (int off = 32; off; off >>= 1) m = fmaxf(m, __shfl_xor(m, off));
                e0 = __expf(e0 - m); e1 = __expf(e1 - m);
                p_s[lane][h] = e0; p_s[lane + 64][h] = e1;
                float l2 = e0 + e1;
#pragma unroll
                for (int off = 32; off; off >>= 1) l2 += __shfl_xor(l2, off);
                if (lane == 0) {
                    int idx = ((b * ASPLIT + split) * 16 + h) * 2;
                    pml[idx] = m; pml[idx + 1] = l2;
                }
            }
        }
        const float* kb = kbuf[t & 1];
        if (t < 8) {
            float4 acc = {0, 0, 0, 0};
            const float* rowp = kb + qr * 128;
#pragma unroll
            for (int j = 0; j < 32; ++j) {
                int g = (j + qr) & 31;
                float4 k4 = *(const float4*)(rowp + g * 4);
                acc.x = fmaf(k4.x, qrot[j].x, acc.x);
                acc.y = fmaf(k4.y, qrot[j].y, acc.y);
                acc.z = fmaf(k4.z, qrot[j].z, acc.z);
                acc.w = fmaf(k4.w, qrot[j].w, acc.w);
            }
            p_s[t * 16 + qpos][qhead] = (acc.x + acc.y + acc.z + acc.w) * SCALE;
        } else {
            int s = t - 8;
            const float* vrow = kb + vkvh * 128 + c16 * 4;
#pragma unroll
            for (int p = 0; p < 16; ++p) {
                float pw = p_s[s * 16 + p][vh];
                float4 v0 = *(const float4*)(vrow + p * 512);
                float4 v1 = *(const float4*)(vrow + p * 512 + 64);
                av0.x = fmaf(pw, v0.x, av0.x); av0.y = fmaf(pw, v0.y, av0.y);
                av0.z = fmaf(pw, v0.z, av0.z); av0.w = fmaf(pw, v0.w, av0.w);
                av1.x = fmaf(pw, v1.x, av1.x); av1.y = fmaf(pw, v1.y, av1.y);
                av1.z = fmaf(pw, v1.z, av1.z); av1.w = fmaf(pw, v1.w, av1.w);
            }
        }
        LG_WAIT0; SCHED0; SBAR;
    }
    size_t pbase = ((size_t)(b * ASPLIT + split) * 16 + vh) * HDIM;
    *(float4*)(pacc + pbase + c16 * 4) = av0;
    *(float4*)(pacc + pbase + 64 + c16 * 4) = av1;
}

// combine split partials: grid 512 = (b, h), 128 threads; writes yT
__global__ void attn_combine_kernel(const float* __restrict__ pml,
                                    const float* __restrict__ pacc, float* __restrict__ yT) {
    int bid = blockIdx.x;
    int b = bid >> 4, h = bid & 15;
    int d = threadIdx.x;
    float M = -INFINITY;
#pragma unroll 8
    for (int s = 0; s < ASPLIT; ++s)
        M = fmaxf(M, pml[((b * ASPLIT + s) * 16 + h) * 2]);
    float denom = 0.f, acc = 0.f;
#pragma unroll 4
    for (int s = 0; s < ASPLIT; ++s) {
        int idx = (b * ASPLIT + s) * 16 + h;
        float e = __expf(pml[idx * 2] - M);
        denom += pml[idx * 2 + 1] * e;
        acc += e * pacc[(size_t)idx * HDIM + d];
    }
    yT[(size_t)(h * HDIM + d) * 32 + b] = acc / denom;
}

__global__ void silu_mul_kernel(float* __restrict__ g1, const float* __restrict__ g2) {
    int i = blockIdx.x * 256 + threadIdx.x; // 262144
    float a = g1[i], bb = g2[i];
    g1[i] = a * bb / (1.f + __expf(-a));
}

extern "C" void kernel_launch(void* const* d_in, const int* in_sizes, int n_in,
                              void* d_out, int out_size, void* d_ws, size_t ws_size,
                              hipStream_t stream) {
    (void)in_sizes; (void)n_in; (void)out_size; (void)ws_size;
    const float* x    = (const float*)d_in[0];
    const float* cosb = (const float*)d_in[1];
    const float* sinb = (const float*)d_in[2];
    const float* kc   = (const float*)d_in[3];
    const float* vc   = (const float*)d_in[4];
    const float* wra  = (const float*)d_in[5];
    const float* wq   = (const float*)d_in[6];
    const float* wk   = (const float*)d_in[7];
    const float* wv   = (const float*)d_in[8];
    const float* wo   = (const float*)d_in[9];
    const float* wrf  = (const float*)d_in[10];
    const float* w1   = (const float*)d_in[11];
    const float* w2   = (const float*)d_in[12];
    const float* w3   = (const float*)d_in[13];
    float* out = (float*)d_out;
    float* ws  = (float*)d_ws;

    float* qn   = ws + OFF_QT;
    float* kT   = ws + OFF_KT;
    float* vT   = ws + OFF_VT;
    float* g1T  = ws + OFF_G1;
    float* g2T  = ws + OFF_G2;
    float* xaT  = ws + OFF_XAT;
    float* rk   = ws + OFF_RK;
    float* rv   = ws + OFF_RV;
    float* pml  = ws + OFF_PML;
    float* pacc = ws + OFF_PACC;
    float* yT   = ws + OFF_YT;
    float* h    = ws + OFF_H;
    float* xfT  = ws + OFF_XFT;
    float* kfix = ws + OFF_KFIX;
    float* vfix = ws + OFF_VFIX;

    // zero all atomic-accumulated buffers (qn,kT,vT,g1,g2 contiguous)
    zero_kernel<<<ZERO_N / 256, 256, 0, stream>>>(ws);

    // xaT = rmsnorm(x)^T, h = x
    rmsnorm_kernel<<<32, 256, 0, stream>>>(x, wra, xaT, h);
    // q (NORMAL layout for attn register loads), k/v (transposed for rope)
    gemv32_kernel<2048, 32, false><<<dim3(8, 64), 256, 0, stream>>>(xaT, wq, qn);
    gemv32_dual_kernel<512, 32, 2><<<dim3(4, 64), 256, 0, stream>>>(xaT, wk, wv, kT, vT);
    // rope new k,v (cache NOT mutated), then build patched last-16 records
    rope_kernel<<<32, 256, 0, stream>>>(kT, vT, cosb, sinb, rk, rv);
    fixlast_kernel<<<1024, 256, 0, stream>>>(kc, vc, rk, rv, kfix, vfix);
    // attention
    attn_stage_kernel<<<1024, 256, 0, stream>>>(qn, kc, vc, kfix, vfix, pml, pacc);
    attn_combine_kernel<<<512, 128, 0, stream>>>(pml, pacc, yT);
    // h = x + y @ wo
    gemv32_kernel<2048, 32, false><<<dim3(8, 64), 256, 0, stream>>>(yT, wo, h);
    // xfT = rmsnorm(h)^T, out = h
    rmsnorm_kernel<<<32, 256, 0, stream>>>(h, wrf, xfT, out);
    // g1 = xf@w1, g2 = xf@w2 (transposed outputs)
    gemv32_dual_kernel<8192, 128, 32><<<dim3(64, 16), 256, 0, stream>>>(xfT, w1, w2, g1T, g2T);
    // g1 = silu(g1)*g2 (elementwise, layout-agnostic)
    silu_mul_kernel<<<1024, 256, 0, stream>>>(g1T, g2T);
    // out += g1 @ w3
    gemv32_kernel<2048, 128, false><<<dim3(8, 64), 256, 0, stream>>>(g1T, w3, out);
}